// Round 4
// baseline (1069.384 us; speedup 1.0000x reference)
//
#include <hip/hip_runtime.h>
#include <hip/hip_bf16.h>
#include <math.h>

typedef __bf16 bf16_t;
typedef __bf16 bf16x4 __attribute__((ext_vector_type(4)));
typedef __bf16 bf16x8 __attribute__((ext_vector_type(8)));
typedef float  f32x4  __attribute__((ext_vector_type(4)));

#define QKV_SCALE 0.17677669529663687f   // 32^-0.5

// workspace offsets (bytes)
#define WS_QKVWT   0u          // [384][128] bf16, row n = original out-col (Q rows pre-scaled)
#define WS_PROJWT  98304u      // [128][128] bf16
#define WS_QKVB    131072u     // [384] f32 (Q entries pre-scaled)
#define WS_BM      135168u     // [256][64][64] f32  (mask + mlp bias, padded)

// ---------------------------------------------------------------- prep ----
__global__ __launch_bounds__(256) void prep_kernel(
    const float* __restrict__ mask,
    const float* __restrict__ qkv_w, const float* __restrict__ qkv_b,
    const float* __restrict__ mlp_w1, const float* __restrict__ mlp_b1,
    const float* __restrict__ mlp_w2, const float* __restrict__ mlp_b2,
    const float* __restrict__ proj_w,
    bf16_t* __restrict__ qkv_wT, bf16_t* __restrict__ proj_wT,
    float* __restrict__ qkv_bs, float* __restrict__ bm)
{
    const int blk = blockIdx.x;
    const int tid = threadIdx.x;
    if (blk < 16) {
        // bias+mask table, [wi*4+h][q(64)][kk(64)]
        const int cell = blk * 256 + tid;          // 0..4095
        const int q = cell >> 6, kk = cell & 63;
        if (q < 49 && kk < 49) {
            const float dy = (float)(q / 7 - kk / 7) * (1.0f / 6.0f);
            const float dx = (float)(q % 7 - kk % 7) * (1.0f / 6.0f);
            float b0 = mlp_b2[0], b1 = mlp_b2[1], b2 = mlp_b2[2], b3 = mlp_b2[3];
            for (int j = 0; j < 64; ++j) {
                const float pre = dy * mlp_w1[j] + dx * mlp_w1[64 + j] + mlp_b1[j];
                const float g = 0.5f * pre * (1.0f + erff(pre * 0.70710678118654752f));
                b0 += g * mlp_w2[j * 4 + 0];
                b1 += g * mlp_w2[j * 4 + 1];
                b2 += g * mlp_w2[j * 4 + 2];
                b3 += g * mlp_w2[j * 4 + 3];
            }
            const int nm = q * 49 + kk;
            for (int wi = 0; wi < 64; ++wi) {
                const float mv = mask[wi * 2401 + nm];
                bm[(size_t)((wi * 4 + 0) << 12) + cell] = mv + b0;
                bm[(size_t)((wi * 4 + 1) << 12) + cell] = mv + b1;
                bm[(size_t)((wi * 4 + 2) << 12) + cell] = mv + b2;
                bm[(size_t)((wi * 4 + 3) << 12) + cell] = mv + b3;
            }
        } else {
            const float val = (kk >= 49) ? -3.0e38f : 0.0f;   // kk-pad masked; q-pad harmless
            for (int t = 0; t < 256; ++t)
                bm[(size_t)(t << 12) + cell] = val;
        }
    } else if (blk < 208) {
        const int idx = (blk - 16) * 256 + tid;    // 0..49151
        const int n = idx >> 7, k = idx & 127;
        float v = qkv_w[k * 384 + n];
        if (n < 128) v *= QKV_SCALE;               // fold Q scale into weights
        qkv_wT[idx] = (bf16_t)v;
    } else if (blk < 272) {
        const int idx = (blk - 208) * 256 + tid;   // 0..16383
        const int n = idx >> 7, k = idx & 127;
        proj_wT[idx] = (bf16_t)proj_w[k * 128 + n];
    } else {
        if (tid < 384) {
            float v = qkv_b[tid];
            if (tid < 128) v *= QKV_SCALE;
            qkv_bs[tid] = v;
        }
    }
}

// ---------------------------------------------------------------- main ----
// Register-resident attention core; LDS only for the 16 KiB cross-head os
// buffer [64 tok][128 dim] bf16, swizzle byte ^= ((tok&7)<<4) on write+read.
__global__ __launch_bounds__(256) __attribute__((amdgpu_waves_per_eu(4, 4)))
void swin_main_kernel(
    const float* __restrict__ x,
    const bf16_t* __restrict__ qkv_wT,
    const bf16_t* __restrict__ proj_wT,
    const float* __restrict__ qkv_bs,
    const float* __restrict__ proj_b,
    const float* __restrict__ bm,
    float* __restrict__ out)
{
    __shared__ __align__(16) unsigned char smem[16384];

    const int b    = blockIdx.x;
    const int tid  = threadIdx.x;
    const int w    = tid >> 6;          // wave = head
    const int lane = tid & 63;
    const int c16  = lane & 15;
    const int q4   = lane >> 4;
    const int swz  = (c16 & 7) << 4;
    const float* xg = x + (size_t)b * 6272;
    const f32x4 zf = {0.f, 0.f, 0.f, 0.f};

    bool tv[4];
#pragma unroll
    for (int nt = 0; nt < 4; ++nt) tv[nt] = (c16 + 16 * nt) < 49;

    const int colQK[4] = {32 * w, 32 * w + 16, 128 + 32 * w, 128 + 32 * w + 16};

    // ================= GEMM1 pass A: Q,K (transposed orientation) =========
    f32x4 qk[4][4];     // [coltile Q0 Q1 K0 K1][token tile]
#pragma unroll
    for (int mt = 0; mt < 4; ++mt)
#pragma unroll
        for (int nt = 0; nt < 4; ++nt) qk[mt][nt] = zf;

#pragma unroll
    for (int ks = 0; ks < 4; ++ks) {
        bf16x8 xf[4];
#pragma unroll
        for (int nt = 0; nt < 4; ++nt) {
            if (tv[nt]) {
                const float* p = xg + (c16 + 16 * nt) * 128 + ks * 32 + q4 * 8;
                float4 a0 = *(const float4*)p;
                float4 a1 = *(const float4*)(p + 4);
                xf[nt][0] = (bf16_t)a0.x; xf[nt][1] = (bf16_t)a0.y;
                xf[nt][2] = (bf16_t)a0.z; xf[nt][3] = (bf16_t)a0.w;
                xf[nt][4] = (bf16_t)a1.x; xf[nt][5] = (bf16_t)a1.y;
                xf[nt][6] = (bf16_t)a1.z; xf[nt][7] = (bf16_t)a1.w;
            } else {
#pragma unroll
                for (int j = 0; j < 8; ++j) xf[nt][j] = (bf16_t)0.0f;
            }
        }
#pragma unroll
        for (int mt = 0; mt < 4; ++mt) {
            const bf16x8 wf = *(const bf16x8*)(qkv_wT + (colQK[mt] + c16) * 128 + ks * 32 + q4 * 8);
#pragma unroll
            for (int nt = 0; nt < 4; ++nt)
                qk[mt][nt] = __builtin_amdgcn_mfma_f32_16x16x32_bf16(wf, xf[nt], qk[mt][nt], 0, 0, 0);
        }
    }

    // pack Q,K fragments: frag[nt] element j <- quad(mt = j>>2)[j&3] + bias
    bf16x8 Qf[4], Kf[4];
    {
        const float4 b0 = *(const float4*)(qkv_bs + colQK[0] + 4 * q4);
        const float4 b1 = *(const float4*)(qkv_bs + colQK[1] + 4 * q4);
        const float4 b2 = *(const float4*)(qkv_bs + colQK[2] + 4 * q4);
        const float4 b3 = *(const float4*)(qkv_bs + colQK[3] + 4 * q4);
#pragma unroll
        for (int nt = 0; nt < 4; ++nt) {
            Qf[nt][0] = (bf16_t)(qk[0][nt][0] + b0.x); Qf[nt][1] = (bf16_t)(qk[0][nt][1] + b0.y);
            Qf[nt][2] = (bf16_t)(qk[0][nt][2] + b0.z); Qf[nt][3] = (bf16_t)(qk[0][nt][3] + b0.w);
            Qf[nt][4] = (bf16_t)(qk[1][nt][0] + b1.x); Qf[nt][5] = (bf16_t)(qk[1][nt][1] + b1.y);
            Qf[nt][6] = (bf16_t)(qk[1][nt][2] + b1.z); Qf[nt][7] = (bf16_t)(qk[1][nt][3] + b1.w);
            Kf[nt][0] = (bf16_t)(qk[2][nt][0] + b2.x); Kf[nt][1] = (bf16_t)(qk[2][nt][1] + b2.y);
            Kf[nt][2] = (bf16_t)(qk[2][nt][2] + b2.z); Kf[nt][3] = (bf16_t)(qk[2][nt][3] + b2.w);
            Kf[nt][4] = (bf16_t)(qk[3][nt][0] + b3.x); Kf[nt][5] = (bf16_t)(qk[3][nt][1] + b3.y);
            Kf[nt][6] = (bf16_t)(qk[3][nt][2] + b3.z); Kf[nt][7] = (bf16_t)(qk[3][nt][3] + b3.w);
        }
    }

    // ================= GEMM1 pass B: V (natural orientation) ==============
    f32x4 va[4][2];     // [token tile][vcol tile]
#pragma unroll
    for (int mt = 0; mt < 4; ++mt) { va[mt][0] = zf; va[mt][1] = zf; }

#pragma unroll
    for (int ks = 0; ks < 4; ++ks) {
        bf16x8 xf[4];
#pragma unroll
        for (int nt = 0; nt < 4; ++nt) {
            if (tv[nt]) {
                const float* p = xg + (c16 + 16 * nt) * 128 + ks * 32 + q4 * 8;
                float4 a0 = *(const float4*)p;
                float4 a1 = *(const float4*)(p + 4);
                xf[nt][0] = (bf16_t)a0.x; xf[nt][1] = (bf16_t)a0.y;
                xf[nt][2] = (bf16_t)a0.z; xf[nt][3] = (bf16_t)a0.w;
                xf[nt][4] = (bf16_t)a1.x; xf[nt][5] = (bf16_t)a1.y;
                xf[nt][6] = (bf16_t)a1.z; xf[nt][7] = (bf16_t)a1.w;
            } else {
#pragma unroll
                for (int j = 0; j < 8; ++j) xf[nt][j] = (bf16_t)0.0f;
            }
        }
#pragma unroll
        for (int ntv = 0; ntv < 2; ++ntv) {
            const bf16x8 vf = *(const bf16x8*)(qkv_wT + (256 + 32 * w + 16 * ntv + c16) * 128 + ks * 32 + q4 * 8);
#pragma unroll
            for (int mt = 0; mt < 4; ++mt)
                va[mt][ntv] = __builtin_amdgcn_mfma_f32_16x16x32_bf16(xf[mt], vf, va[mt][ntv], 0, 0, 0);
        }
    }

    // pack V fragments: Vf[ntv][ksv] element j <- token quad(2ksv + (j>>2))[j&3]
    bf16x8 Vf[2][2];
#pragma unroll
    for (int ntv = 0; ntv < 2; ++ntv) {
        const float qv = qkv_bs[256 + 32 * w + 16 * ntv + c16];
#pragma unroll
        for (int ksv = 0; ksv < 2; ++ksv) {
#pragma unroll
            for (int r = 0; r < 4; ++r) {
                Vf[ntv][ksv][r]     = (bf16_t)(va[2 * ksv][ntv][r] + qv);
                Vf[ntv][ksv][4 + r] = (bf16_t)(va[2 * ksv + 1][ntv][r] + qv);
            }
        }
    }

    // ================= S^T = K · Q^T  (D: lane=q, quads=kk) ===============
    f32x4 st[4][4];     // [kk tile][q tile]
#pragma unroll
    for (int mtk = 0; mtk < 4; ++mtk)
#pragma unroll
        for (int ntq = 0; ntq < 4; ++ntq)
            st[mtk][ntq] = __builtin_amdgcn_mfma_f32_16x16x32_bf16(Kf[mtk], Qf[ntq], zf, 0, 0, 0);

    // ========== softmax + P pack (pre-normalized), per q-tile =============
    const float* bq = bm + ((size_t)(((b & 63) << 2) + w) << 12);
    bf16x8 Pf[4][2];
#pragma unroll
    for (int ntq = 0; ntq < 4; ++ntq) {
        const int q = c16 + 16 * ntq;
        float4 bv[4];
#pragma unroll
        for (int mt = 0; mt < 4; ++mt)
            bv[mt] = *(const float4*)(bq + q * 64 + 16 * mt + 4 * q4);
        float mx = -3.0e38f;
#pragma unroll
        for (int mt = 0; mt < 4; ++mt) {
            st[mt][ntq][0] += bv[mt].x; st[mt][ntq][1] += bv[mt].y;
            st[mt][ntq][2] += bv[mt].z; st[mt][ntq][3] += bv[mt].w;
#pragma unroll
            for (int r = 0; r < 4; ++r) mx = fmaxf(mx, st[mt][ntq][r]);
        }
        mx = fmaxf(mx, __shfl_xor(mx, 16));
        mx = fmaxf(mx, __shfl_xor(mx, 32));
        float sm = 0.0f;
#pragma unroll
        for (int mt = 0; mt < 4; ++mt)
#pragma unroll
            for (int r = 0; r < 4; ++r) {
                const float p = __expf(st[mt][ntq][r] - mx);
                st[mt][ntq][r] = p;
                sm += p;
            }
        sm += __shfl_xor(sm, 16);
        sm += __shfl_xor(sm, 32);
        const float rp = 1.0f / sm;
#pragma unroll
        for (int ksv = 0; ksv < 2; ++ksv) {
#pragma unroll
            for (int r = 0; r < 4; ++r) {
                Pf[ntq][ksv][r]     = (bf16_t)(st[2 * ksv][ntq][r] * rp);
                Pf[ntq][ksv][4 + r] = (bf16_t)(st[2 * ksv + 1][ntq][r] * rp);
            }
        }
    }

    // ================= O^T = V · P^T  (D: lane=q, quads=d) ================
    f32x4 ot[2][4];
#pragma unroll
    for (int ntv = 0; ntv < 2; ++ntv)
#pragma unroll
        for (int ntq = 0; ntq < 4; ++ntq) ot[ntv][ntq] = zf;
#pragma unroll
    for (int ksv = 0; ksv < 2; ++ksv)
#pragma unroll
        for (int ntv = 0; ntv < 2; ++ntv)
#pragma unroll
            for (int ntq = 0; ntq < 4; ++ntq)
                ot[ntv][ntq] = __builtin_amdgcn_mfma_f32_16x16x32_bf16(Vf[ntv][ksv], Pf[ntq][ksv], ot[ntv][ntq], 0, 0, 0);

    // ---- O^T -> os [tok][128] bf16 (b64 packed, swizzled) ----
#pragma unroll
    for (int ntv = 0; ntv < 2; ++ntv)
#pragma unroll
        for (int ntq = 0; ntq < 4; ++ntq) {
            const int tok = c16 + 16 * ntq;
            bf16x4 pk;
#pragma unroll
            for (int r = 0; r < 4; ++r) pk[r] = (bf16_t)ot[ntv][ntq][r];
            *(bf16x4*)&smem[(tok * 256 + (32 * w + 16 * ntv + 4 * q4) * 2) ^ swz] = pk;
        }
    __syncthreads();

    // ===== proj as Y^T with interleaved ocol tiles: lane owns 8 consec ====
    f32x4 pj[2][4];
#pragma unroll
    for (int mt = 0; mt < 2; ++mt)
#pragma unroll
        for (int ntq = 0; ntq < 4; ++ntq) pj[mt][ntq] = zf;

    const int oc_il = 32 * w + 8 * (c16 >> 2) + (c16 & 3);   // tile mt adds 4*mt
#pragma unroll
    for (int ks = 0; ks < 4; ++ks) {
        const bf16x8 aw0 = *(const bf16x8*)(proj_wT + (oc_il + 0) * 128 + ks * 32 + q4 * 8);
        const bf16x8 aw1 = *(const bf16x8*)(proj_wT + (oc_il + 4) * 128 + ks * 32 + q4 * 8);
#pragma unroll
        for (int ntq = 0; ntq < 4; ++ntq) {
            const bf16x8 bo = *(const bf16x8*)&smem[((c16 + 16 * ntq) * 256 + ks * 64 + q4 * 16) ^ swz];
            pj[0][ntq] = __builtin_amdgcn_mfma_f32_16x16x32_bf16(aw0, bo, pj[0][ntq], 0, 0, 0);
            pj[1][ntq] = __builtin_amdgcn_mfma_f32_16x16x32_bf16(aw1, bo, pj[1][ntq], 0, 0, 0);
        }
    }

    // ---- store: lane writes 32 contiguous bytes (2x float4) per q-tile ----
    float* og = out + (size_t)b * 6272;
    const int oc0 = 32 * w + 8 * q4;
    const float4 pb0 = *(const float4*)(proj_b + oc0);
    const float4 pb1 = *(const float4*)(proj_b + oc0 + 4);
#pragma unroll
    for (int ntq = 0; ntq < 4; ++ntq) {
        const int tok = c16 + 16 * ntq;
        if (tok < 49) {
            float4 v0, v1;
            v0.x = pj[0][ntq][0] + pb0.x; v0.y = pj[0][ntq][1] + pb0.y;
            v0.z = pj[0][ntq][2] + pb0.z; v0.w = pj[0][ntq][3] + pb0.w;
            v1.x = pj[1][ntq][0] + pb1.x; v1.y = pj[1][ntq][1] + pb1.y;
            v1.z = pj[1][ntq][2] + pb1.z; v1.w = pj[1][ntq][3] + pb1.w;
            *(float4*)(og + tok * 128 + oc0)     = v0;
            *(float4*)(og + tok * 128 + oc0 + 4) = v1;
        }
    }
}

// -------------------------------------------------------------- launch ----
extern "C" void kernel_launch(void* const* d_in, const int* in_sizes, int n_in,
                              void* d_out, int out_size, void* d_ws, size_t ws_size,
                              hipStream_t stream) {
    const float* x      = (const float*)d_in[0];
    const float* mask   = (const float*)d_in[1];
    const float* qkv_w  = (const float*)d_in[2];
    const float* qkv_b  = (const float*)d_in[3];
    const float* mlp_w1 = (const float*)d_in[4];
    const float* mlp_b1 = (const float*)d_in[5];
    const float* mlp_w2 = (const float*)d_in[6];
    const float* mlp_b2 = (const float*)d_in[7];
    const float* proj_w = (const float*)d_in[8];
    const float* proj_b = (const float*)d_in[9];
    float* out = (float*)d_out;

    unsigned char* ws = (unsigned char*)d_ws;
    bf16_t* qkv_wT  = (bf16_t*)(ws + WS_QKVWT);
    bf16_t* proj_wT = (bf16_t*)(ws + WS_PROJWT);
    float*  qkv_bs  = (float*)(ws + WS_QKVB);
    float*  bm      = (float*)(ws + WS_BM);

    hipLaunchKernelGGL(prep_kernel, dim3(273), dim3(256), 0, stream,
                       mask, qkv_w, qkv_b, mlp_w1, mlp_b1, mlp_w2, mlp_b2, proj_w,
                       qkv_wT, proj_wT, qkv_bs, bm);
    hipLaunchKernelGGL(swin_main_kernel, dim3(16384), dim3(256), 0, stream,
                       x, qkv_wT, proj_wT, qkv_bs, proj_b, bm, out);
}